// Round 3
// baseline (376.870 us; speedup 1.0000x reference)
//
#include <hip/hip_runtime.h>

#define VDIM 20000
#define EDIM 128
#define BATCH 64
#define SEQ 100

typedef float f32x4 __attribute__((ext_vector_type(4)));
typedef short bf16x8 __attribute__((ext_vector_type(8)));
typedef unsigned short ushortx8 __attribute__((ext_vector_type(8)));

__device__ __forceinline__ unsigned short f2bf(float f) {
  unsigned u = __builtin_bit_cast(unsigned, f);
  u += 0x7FFFu + ((u >> 16) & 1u);   // RTNE
  return (unsigned short)(u >> 16);
}

// ---- fused prep: W->bf16 conversion (blocks 0..1249) + A gather (1250..1377)
__global__ void prep_kernel(const float* __restrict__ Wi, const float* __restrict__ Wu,
                            const int* __restrict__ attr_item, const int* __restrict__ attr_user,
                            const int* __restrict__ item_ids, const int* __restrict__ user_ids,
                            const float* __restrict__ item_emb, const float* __restrict__ user_emb,
                            unsigned short* __restrict__ wbf, unsigned short* __restrict__ abf) {
  const int bid = blockIdx.x, t = threadIdx.x;
  if (bid < 1250) {
    const int i0 = (bid * 256 + t) * 8;
    #pragma unroll
    for (int c = 0; c < 2; ++c) {
      const float* src = c ? Wu : Wi;
      unsigned short* dst = wbf + (size_t)c * (VDIM * EDIM);
      float4 a = *(const float4*)(src + i0);
      float4 b = *(const float4*)(src + i0 + 4);
      ushortx8 o;
      o[0] = f2bf(a.x); o[1] = f2bf(a.y); o[2] = f2bf(a.z); o[3] = f2bf(a.w);
      o[4] = f2bf(b.x); o[5] = f2bf(b.y); o[6] = f2bf(b.z); o[7] = f2bf(b.w);
      *(ushortx8*)(dst + i0) = o;
    }
  } else {
    const int g = bid - 1250;
    const int b = g & 63, c = g >> 6;
    const int r = t >> 1, h = t & 1;
    const int* ids = c ? attr_user : attr_item;
    const float* W = c ? Wu : Wi;
    const float* demb = c ? user_emb : item_emb;
    const int* dids = c ? user_ids : item_ids;
    unsigned short* dst = abf + (((size_t)(c * BATCH + b) * 128 + r) * EDIM) + h * 64;
    const float* src = nullptr;
    if (r < SEQ)       src = W + (size_t)ids[b * SEQ + r] * EDIM + h * 64;
    else if (r == SEQ) src = demb + (size_t)dids[b] * EDIM + h * 64;
    if (src) {
      #pragma unroll
      for (int i = 0; i < 8; ++i) {
        float4 a  = *(const float4*)(src + i * 8);
        float4 bb = *(const float4*)(src + i * 8 + 4);
        ushortx8 o;
        o[0] = f2bf(a.x);  o[1] = f2bf(a.y);  o[2] = f2bf(a.z);  o[3] = f2bf(a.w);
        o[4] = f2bf(bb.x); o[5] = f2bf(bb.y); o[6] = f2bf(bb.z); o[7] = f2bf(bb.w);
        *(ushortx8*)(dst + i * 8) = o;
      }
    } else {
      ushortx8 z = {0, 0, 0, 0, 0, 0, 0, 0};
      #pragma unroll
      for (int i = 0; i < 8; ++i) *(ushortx8*)(dst + i * 8) = z;
    }
  }
}

// ---- main: B-fragments held in registers across all b-stages ----
// block = 512 thr (8 waves: wm 0..3 x wn 0..1); tile = 128 rows (one b) x 256 cols
// 8 stages: 4 b's x 2 clusters. Only A flows through LDS (double-buffered 32KB).
__global__ __launch_bounds__(512, 1) void main_kernel(
    const unsigned short* __restrict__ wbf, const unsigned short* __restrict__ abf,
    const float* __restrict__ tf_item, const int* __restrict__ lens_item,
    const float* __restrict__ tf_user, const int* __restrict__ lens_user,
    float* __restrict__ out) {
  __shared__ __align__(16) unsigned char sA[2][32768];
  __shared__ float sDen[2][4][256];
  __shared__ float sNum[2][4][256];
  __shared__ float sDir[2][256];

  const int t = threadIdx.x;
  const int bg4 = blockIdx.x * 4;          // 16 b-groups
  const int v0 = blockIdx.y * 256;         // 79 v-tiles
  const int lane = t & 63, wave = t >> 6;
  const int wm = wave >> 1, wn = wave & 1;
  const int quad = lane >> 4, l15 = lane & 15;

  const uint4* abfq = (const uint4*)abf;
  const unsigned short* wb1 = wbf + (size_t)VDIM * EDIM;

  // ---- B fragments for cluster 0 (held in 128 VGPRs) ----
  bf16x8 breg[8][4];
  {
    #pragma unroll
    for (int nt = 0; nt < 8; ++nt) {
      const int v = v0 + wn * 128 + nt * 16 + l15;
      const unsigned short* p = wbf + (size_t)v * EDIM + quad * 8;
      const bool ok = (v < VDIM);
      #pragma unroll
      for (int ks = 0; ks < 4; ++ks) {
        bf16x8 z = {0, 0, 0, 0, 0, 0, 0, 0};
        breg[nt][ks] = ok ? *(const bf16x8*)(p + ks * 32) : z;
      }
    }
  }

  // ---- prefetch + stage A for stage 0 ----
  uint4 pa[4];
  {
    const uint4* src = abfq + (size_t)bg4 * 2048;   // c=0, b=bg4
    #pragma unroll
    for (int i = 0; i < 4; ++i) pa[i] = src[t + 512 * i];
  }
  #pragma unroll
  for (int i = 0; i < 4; ++i) {
    int ch = t + 512 * i, r = ch >> 4, j = ch & 15;
    *(uint4*)(&sA[0][r * 256 + ((j ^ (r & 15)) << 4)]) = pa[i];
  }
  __syncthreads();

  float res[4] = {0.f, 0.f, 0.f, 0.f};

  #pragma unroll 1
  for (int s = 0; s < 8; ++s) {
    const int c = s >> 2, it = s & 3, b = bg4 + it;
    const int buf = s & 1;

    // issue next stage's A prefetch early (latency hidden under MFMA+epilogue)
    if (s < 7) {
      const int ns = s + 1;
      const uint4* src = abfq + (size_t)((ns >> 2) * BATCH + bg4 + (ns & 3)) * 2048;
      #pragma unroll
      for (int i = 0; i < 4; ++i) pa[i] = src[t + 512 * i];
    }

    // ---- GEMM: 2x8 tiles of 16x16x32, A from LDS, B from registers ----
    f32x4 acc[2][8];
    #pragma unroll
    for (int mt = 0; mt < 2; ++mt)
      #pragma unroll
      for (int nt = 0; nt < 8; ++nt) { f32x4 z = {0.f, 0.f, 0.f, 0.f}; acc[mt][nt] = z; }

    const unsigned char* pAb = sA[buf] + (wm * 32) * 256;
    #pragma unroll
    for (int ks = 0; ks < 4; ++ks) {
      const int j = ks * 4 + quad;
      const int sw = (j ^ l15) << 4;
      bf16x8 a0 = *(const bf16x8*)(pAb + l15 * 256 + sw);
      bf16x8 a1 = *(const bf16x8*)(pAb + (16 + l15) * 256 + sw);
      #pragma unroll
      for (int nt = 0; nt < 8; ++nt) {
        acc[0][nt] = __builtin_amdgcn_mfma_f32_16x16x32_bf16(a0, breg[nt][ks], acc[0][nt], 0, 0, 0);
        acc[1][nt] = __builtin_amdgcn_mfma_f32_16x16x32_bf16(a1, breg[nt][ks], acc[1][nt], 0, 0, 0);
      }
    }

    // reload B fragments for cluster 1 (latency hidden under epilogue)
    if (s == 3) {
      #pragma unroll
      for (int nt = 0; nt < 8; ++nt) {
        const int v = v0 + wn * 128 + nt * 16 + l15;
        const unsigned short* p = wb1 + (size_t)v * EDIM + quad * 8;
        const bool ok = (v < VDIM);
        #pragma unroll
        for (int ks = 0; ks < 4; ++ks) {
          bf16x8 z = {0, 0, 0, 0, 0, 0, 0, 0};
          breg[nt][ks] = ok ? *(const bf16x8*)(p + ks * 32) : z;
        }
      }
    }

    // ---- epilogue: softmax partials ----
    const float* tf = c ? tf_user : tf_item;
    const int* ln = c ? lens_user : lens_item;
    const int lenb = ln[b];
    float wv[2][4];
    #pragma unroll
    for (int mt = 0; mt < 2; ++mt)
      #pragma unroll
      for (int r = 0; r < 4; ++r) {
        const int row = wm * 32 + mt * 16 + quad * 4 + r;
        wv[mt][r] = (row < lenb) ? tf[b * SEQ + row] : 0.f;
      }

    #pragma unroll
    for (int nt = 0; nt < 8; ++nt) {
      float den = 0.f, num = 0.f;
      #pragma unroll
      for (int mt = 0; mt < 2; ++mt)
        #pragma unroll
        for (int r = 0; r < 4; ++r) {
          const float v = acc[mt][nt][r];
          const float e = __expf(v);
          den += e;
          num = fmaf(wv[mt][r], e * v, num);
        }
      den += __shfl_xor(den, 16, 64);
      den += __shfl_xor(den, 32, 64);
      num += __shfl_xor(num, 16, 64);
      num += __shfl_xor(num, 32, 64);
      const int col = wn * 128 + nt * 16 + l15;
      if (quad == 0) {
        sDen[buf][wm][col] = den;
        sNum[buf][wm][col] = num;
      }
      if (wm == 3 && quad == 1) sDir[buf][col] = acc[0][nt][0];   // row 100
    }

    // stage next A into the other buffer (waits on the early prefetch)
    if (s < 7) {
      #pragma unroll
      for (int i = 0; i < 4; ++i) {
        int ch = t + 512 * i, r = ch >> 4, j = ch & 15;
        *(uint4*)(&sA[buf ^ 1][r * 256 + ((j ^ (r & 15)) << 4)]) = pa[i];
      }
    }
    __syncthreads();

    // ---- combine (parity arrays: race-free across the single barrier) ----
    if (t < 256) {
      float den = sDen[buf][0][t] + sDen[buf][1][t] + sDen[buf][2][t] + sDen[buf][3][t];
      float num = sNum[buf][0][t] + sNum[buf][1][t] + sNum[buf][2][t] + sNum[buf][3][t];
      float dir = sDir[buf][t];
      den -= 27.f + __expf(dir);   // 27 zero-pad rows + the direct row
      res[it] += num / den + dir;
    }
  }

  if (t < 256) {
    const int v = v0 + t;
    if (v < VDIM) {
      #pragma unroll
      for (int it = 0; it < 4; ++it)
        out[(size_t)(bg4 + it) * VDIM + v] = res[it];
    }
  }
}

extern "C" void kernel_launch(void* const* d_in, const int* in_sizes, int n_in,
                              void* d_out, int out_size, void* d_ws, size_t ws_size,
                              hipStream_t stream) {
  const int*   attr_item = (const int*)d_in[0];
  const float* tf_item   = (const float*)d_in[1];
  const int*   lens_item = (const int*)d_in[2];
  const int*   item_ids  = (const int*)d_in[3];
  const int*   attr_user = (const int*)d_in[4];
  const float* tf_user   = (const float*)d_in[5];
  const int*   lens_user = (const int*)d_in[6];
  const int*   user_ids  = (const int*)d_in[7];
  const float* W_item    = (const float*)d_in[8];
  const float* W_user    = (const float*)d_in[9];
  const float* user_emb  = (const float*)d_in[10];
  const float* item_emb  = (const float*)d_in[11];
  float* out = (float*)d_out;

  unsigned short* wbf = (unsigned short*)d_ws;                  // [2][V][E] bf16
  unsigned short* abf = wbf + (size_t)2 * VDIM * EDIM;          // [2][64][128][E] bf16

  prep_kernel<<<dim3(1250 + 128), 256, 0, stream>>>(W_item, W_user, attr_item, attr_user,
                                                    item_ids, user_ids, item_emb, user_emb,
                                                    wbf, abf);
  main_kernel<<<dim3(16, 79), 512, 0, stream>>>(wbf, abf, tf_item, lens_item,
                                                tf_user, lens_user, out);
}

// Round 4
// 370.152 us; speedup vs baseline: 1.0181x; 1.0181x over previous
//
#include <hip/hip_runtime.h>

#define VDIM 20000
#define EDIM 128
#define BATCH 64
#define SEQ 100

typedef float f32x4 __attribute__((ext_vector_type(4)));
typedef short bf16x8 __attribute__((ext_vector_type(8)));
typedef unsigned short ushortx8 __attribute__((ext_vector_type(8)));

__device__ __forceinline__ unsigned short f2bf(float f) {
  unsigned u = __builtin_bit_cast(unsigned, f);
  u += 0x7FFFu + ((u >> 16) & 1u);   // RTNE
  return (unsigned short)(u >> 16);
}

// ---- fused prep: W->bf16 conversion (blocks 0..2499) + A gather (2500..2627)
__global__ void prep_kernel(const float* __restrict__ Wi, const float* __restrict__ Wu,
                            const int* __restrict__ attr_item, const int* __restrict__ attr_user,
                            const int* __restrict__ item_ids, const int* __restrict__ user_ids,
                            const float* __restrict__ item_emb, const float* __restrict__ user_emb,
                            unsigned short* __restrict__ wbf, unsigned short* __restrict__ abf) {
  const int bid = blockIdx.x, t = threadIdx.x;
  if (bid < 2500) {
    const int c = bid & 1;
    const float* src = c ? Wu : Wi;
    unsigned short* dst = wbf + (size_t)c * (VDIM * EDIM);
    const int i0 = ((bid >> 1) * 256 + t) * 8;
    float4 a = *(const float4*)(src + i0);
    float4 b = *(const float4*)(src + i0 + 4);
    ushortx8 o;
    o[0] = f2bf(a.x); o[1] = f2bf(a.y); o[2] = f2bf(a.z); o[3] = f2bf(a.w);
    o[4] = f2bf(b.x); o[5] = f2bf(b.y); o[6] = f2bf(b.z); o[7] = f2bf(b.w);
    *(ushortx8*)(dst + i0) = o;
  } else {
    const int g = bid - 2500;
    const int b = g & 63, c = g >> 6;
    const int r = t >> 1, h = t & 1;
    const int* ids = c ? attr_user : attr_item;
    const float* W = c ? Wu : Wi;
    const float* demb = c ? user_emb : item_emb;
    const int* dids = c ? user_ids : item_ids;
    unsigned short* dst = abf + (((size_t)(c * BATCH + b) * 128 + r) * EDIM) + h * 64;
    const float* src = nullptr;
    if (r < SEQ)       src = W + (size_t)ids[b * SEQ + r] * EDIM + h * 64;
    else if (r == SEQ) src = demb + (size_t)dids[b] * EDIM + h * 64;
    if (src) {
      #pragma unroll
      for (int i = 0; i < 8; ++i) {
        float4 a  = *(const float4*)(src + i * 8);
        float4 bb = *(const float4*)(src + i * 8 + 4);
        ushortx8 o;
        o[0] = f2bf(a.x);  o[1] = f2bf(a.y);  o[2] = f2bf(a.z);  o[3] = f2bf(a.w);
        o[4] = f2bf(bb.x); o[5] = f2bf(bb.y); o[6] = f2bf(bb.z); o[7] = f2bf(bb.w);
        *(ushortx8*)(dst + i * 8) = o;
      }
    } else {
      ushortx8 z = {0, 0, 0, 0, 0, 0, 0, 0};
      #pragma unroll
      for (int i = 0; i < 8; ++i) *(ushortx8*)(dst + i * 8) = z;
    }
  }
}

// ---- main: barrier-free stage loop ----
// block = 512 thr (8 waves: wm 0..3 x wn 0..1); tile = 128 rows (one b) x 256 cols.
// B held in 128 VGPRs (reloaded once at s==3). A-fragments loaded DIRECTLY from
// global (pre-gathered bf16, L1/L2-served), prefetched one stage ahead.
// Per-stage partials go to per-stage LDS slots; ONE barrier at the end.
__global__ __launch_bounds__(512) __attribute__((amdgpu_waves_per_eu(2, 2)))
void main_kernel(const unsigned short* __restrict__ wbf, const unsigned short* __restrict__ abf,
                 const float* __restrict__ tf_item, const int* __restrict__ lens_item,
                 const float* __restrict__ tf_user, const int* __restrict__ lens_user,
                 float* __restrict__ out) {
  __shared__ float sDen[8][4][256];
  __shared__ float sNum[8][4][256];
  __shared__ float sDir[8][256];

  const int t = threadIdx.x;
  const int v0 = blockIdx.x * 256;         // 79 v-tiles
  const int bg4 = blockIdx.y * 4;          // 16 b-groups
  const int lane = t & 63, wave = t >> 6;
  const int wm = wave >> 1, wn = wave & 1;
  const int quad = lane >> 4, l15 = lane & 15;

  // ---- B fragments for cluster 0 (128 VGPRs) ----
  bf16x8 breg[8][4];
  #pragma unroll
  for (int nt = 0; nt < 8; ++nt) {
    const int v = v0 + wn * 128 + nt * 16 + l15;
    const unsigned short* p = wbf + (size_t)v * EDIM + quad * 8;
    const bool ok = (v < VDIM);
    #pragma unroll
    for (int ks = 0; ks < 4; ++ks) {
      bf16x8 z = {0, 0, 0, 0, 0, 0, 0, 0};
      breg[nt][ks] = ok ? *(const bf16x8*)(p + ks * 32) : z;
    }
  }

  // ---- A fragments for stage 0 (direct global, 32 VGPRs) ----
  const int aoff = (wm * 32 + l15) * EDIM + quad * 8;
  bf16x8 af[2][4];
  {
    const unsigned short* aB = abf + (size_t)bg4 * (128 * EDIM);
    #pragma unroll
    for (int mt = 0; mt < 2; ++mt)
      #pragma unroll
      for (int ks = 0; ks < 4; ++ks)
        af[mt][ks] = *(const bf16x8*)(aB + aoff + mt * 16 * EDIM + ks * 32);
  }

  #pragma unroll 1
  for (int s = 0; s < 8; ++s) {
    const int c = s >> 2, it = s & 3, b = bg4 + it;

    // ---- GEMM: 2x8 tiles of 16x16x32, A+B both from registers ----
    f32x4 acc[2][8];
    #pragma unroll
    for (int mt = 0; mt < 2; ++mt)
      #pragma unroll
      for (int nt = 0; nt < 8; ++nt) { f32x4 z = {0.f, 0.f, 0.f, 0.f}; acc[mt][nt] = z; }

    #pragma unroll
    for (int ks = 0; ks < 4; ++ks) {
      #pragma unroll
      for (int nt = 0; nt < 8; ++nt) {
        acc[0][nt] = __builtin_amdgcn_mfma_f32_16x16x32_bf16(af[0][ks], breg[nt][ks], acc[0][nt], 0, 0, 0);
        acc[1][nt] = __builtin_amdgcn_mfma_f32_16x16x32_bf16(af[1][ks], breg[nt][ks], acc[1][nt], 0, 0, 0);
      }
    }

    // prefetch next stage's A (latency hidden under epilogue VALU)
    if (s < 7) {
      const int ns = s + 1;
      const unsigned short* aB = abf + (size_t)((ns >> 2) * BATCH + bg4 + (ns & 3)) * (128 * EDIM);
      #pragma unroll
      for (int mt = 0; mt < 2; ++mt)
        #pragma unroll
        for (int ks = 0; ks < 4; ++ks)
          af[mt][ks] = *(const bf16x8*)(aB + aoff + mt * 16 * EDIM + ks * 32);
    }
    // reload B for cluster 1 once (latency hidden under epilogue)
    if (s == 3) {
      const unsigned short* wb1 = wbf + (size_t)VDIM * EDIM;
      #pragma unroll
      for (int nt = 0; nt < 8; ++nt) {
        const int v = v0 + wn * 128 + nt * 16 + l15;
        const unsigned short* p = wb1 + (size_t)v * EDIM + quad * 8;
        const bool ok = (v < VDIM);
        #pragma unroll
        for (int ks = 0; ks < 4; ++ks) {
          bf16x8 z = {0, 0, 0, 0, 0, 0, 0, 0};
          breg[nt][ks] = ok ? *(const bf16x8*)(p + ks * 32) : z;
        }
      }
    }

    // ---- epilogue: softmax partials into this stage's LDS slot ----
    const float* tf = c ? tf_user : tf_item;
    const int* ln = c ? lens_user : lens_item;
    const int lenb = ln[b];
    float wv[2][4];
    #pragma unroll
    for (int mt = 0; mt < 2; ++mt)
      #pragma unroll
      for (int r = 0; r < 4; ++r) {
        const int row = wm * 32 + mt * 16 + quad * 4 + r;
        wv[mt][r] = (row < lenb) ? tf[b * SEQ + row] : 0.f;
      }

    #pragma unroll
    for (int nt = 0; nt < 8; ++nt) {
      float den = 0.f, num = 0.f;
      #pragma unroll
      for (int mt = 0; mt < 2; ++mt)
        #pragma unroll
        for (int r = 0; r < 4; ++r) {
          const float v = acc[mt][nt][r];
          const float e = __expf(v);
          den += e;
          num = fmaf(wv[mt][r], e * v, num);
        }
      den += __shfl_xor(den, 16, 64);
      den += __shfl_xor(den, 32, 64);
      num += __shfl_xor(num, 16, 64);
      num += __shfl_xor(num, 32, 64);
      const int col = wn * 128 + nt * 16 + l15;
      if (quad == 0) {
        sDen[s][wm][col] = den;
        sNum[s][wm][col] = num;
      }
      if (wm == 3 && quad == 1) sDir[s][col] = acc[0][nt][0];   // row 100
    }
  }

  __syncthreads();   // the ONLY barrier

  // ---- combine all 8 stages ----
  if (t < 256) {
    float res[4] = {0.f, 0.f, 0.f, 0.f};
    #pragma unroll
    for (int s = 0; s < 8; ++s) {
      float den = sDen[s][0][t] + sDen[s][1][t] + sDen[s][2][t] + sDen[s][3][t];
      float num = sNum[s][0][t] + sNum[s][1][t] + sNum[s][2][t] + sNum[s][3][t];
      float dir = sDir[s][t];
      den -= 27.f + __expf(dir);   // 27 zero-pad rows + the direct row
      res[s & 3] += num / den + dir;
    }
    const int v = v0 + t;
    if (v < VDIM) {
      #pragma unroll
      for (int it = 0; it < 4; ++it)
        out[(size_t)(bg4 + it) * VDIM + v] = res[it];
    }
  }
}

extern "C" void kernel_launch(void* const* d_in, const int* in_sizes, int n_in,
                              void* d_out, int out_size, void* d_ws, size_t ws_size,
                              hipStream_t stream) {
  const int*   attr_item = (const int*)d_in[0];
  const float* tf_item   = (const float*)d_in[1];
  const int*   lens_item = (const int*)d_in[2];
  const int*   item_ids  = (const int*)d_in[3];
  const int*   attr_user = (const int*)d_in[4];
  const float* tf_user   = (const float*)d_in[5];
  const int*   lens_user = (const int*)d_in[6];
  const int*   user_ids  = (const int*)d_in[7];
  const float* W_item    = (const float*)d_in[8];
  const float* W_user    = (const float*)d_in[9];
  const float* user_emb  = (const float*)d_in[10];
  const float* item_emb  = (const float*)d_in[11];
  float* out = (float*)d_out;

  unsigned short* wbf = (unsigned short*)d_ws;                  // [2][V][E] bf16
  unsigned short* abf = wbf + (size_t)2 * VDIM * EDIM;          // [2][64][128][E] bf16

  prep_kernel<<<dim3(2500 + 128), 256, 0, stream>>>(W_item, W_user, attr_item, attr_user,
                                                    item_ids, user_ids, item_emb, user_emb,
                                                    wbf, abf);
  main_kernel<<<dim3(79, 16), 512, 0, stream>>>(wbf, abf, tf_item, lens_item,
                                                tf_user, lens_user, out);
}